// Round 1
// baseline (749.339 us; speedup 1.0000x reference)
//
#include <hip/hip_runtime.h>

#define NV 10000
#define NB 4
#define NTT 12
#define NSEQ 48
#define NH 3
#define NE 512
#define NS 32
#define ND 64

// workspace layout (float indices)
#define S_U   0
#define S_C1  64
#define S_V1  128
#define S_V2  192
#define S_SC  256
#define S_GU  272
#define S_GC  528
#define S_G0  784
#define F_INV 1040
#define F_M   (F_INV + NH*NV)
#define F_XT  (F_M + NH*NV)
#define F_AGG (F_XT + NV*NSEQ)
#define F_Y   (F_AGG + NH*NE*NSEQ)
#define F_Z   (F_Y + NH*NV*NSEQ)
#define F_P0  (F_Z + NH*NV*NSEQ)
#define F_Q0  (F_P0 + NV*NSEQ)
#define F_P1  (F_Q0 + NV*NSEQ)
#define F_Q1  (F_P1 + NV*NSEQ)
#define F_END (F_Q1 + NV*NSEQ)
// int region (int indices from ws base)
#define I_CNT  F_END
#define I_CUR  (I_CNT + NH*NV)
#define I_OFF  (I_CUR + NH*NV)
#define I_SLOT (I_OFF + NH*NV)

__device__ __forceinline__ float sigf(float x) {
  return __builtin_amdgcn_rcpf(1.0f + __expf(-x));
}
__device__ __forceinline__ float tanh_fast(float x) {
  return 1.0f - 2.0f * __builtin_amdgcn_rcpf(1.0f + __expf(2.0f * x));
}

// ---------------- small weight precompute ----------------
__global__ void k_prep(const float* __restrict__ w1, const float* __restrict__ b1,
                       const float* __restrict__ w2, const float* __restrict__ b2,
                       const float* __restrict__ attn_w, const float* __restrict__ attn_a,
                       const float* __restrict__ w_ih, const float* __restrict__ b_ih,
                       const float* __restrict__ b_hh, float* __restrict__ ws) {
  __shared__ float u_s[64], c1_s[64];
  const int tid = threadIdx.x;
  if (tid < 64) {
    float v1 = 0.f, v2 = 0.f, u = 0.f, c1 = 0.f;
    for (int d = 0; d < 64; ++d) {
      const float aw = attn_w[tid * 64 + d];
      v1 += aw * attn_a[d];
      v2 += aw * attn_a[64 + d];
      const float w2v = w2[d * 64 + tid];
      u  += w1[d] * w2v;
      c1 += b1[d] * w2v;
    }
    ws[S_U + tid] = u;  ws[S_C1 + tid] = c1;
    ws[S_V1 + tid] = v1; ws[S_V2 + tid] = v2;
    u_s[tid] = u; c1_s[tid] = c1;
  }
  __syncthreads();
  if (tid == 0) {
    float al = 0.f, be = 0.f, ga = 0.f, de = 0.f, ep = 0.f;
    for (int d = 0; d < 64; ++d) {
      const float v1 = ws[S_V1 + d], v2 = ws[S_V2 + d];
      al += u_s[d] * v1;  be += c1_s[d] * v1;
      ga += u_s[d] * v2;  de += c1_s[d] * v2;
      ep += b2[d] * (v1 + v2);
    }
    ws[S_SC + 0] = al; ws[S_SC + 1] = be; ws[S_SC + 2] = ga;
    ws[S_SC + 3] = de; ws[S_SC + 4] = ep;
  }
  {
    const int j = tid;  // 256 threads exactly
    float gu = 0.f, gc = 0.f, g0 = 0.f;
    for (int d = 0; d < 64; ++d) {
      const float w = w_ih[j * 64 + d];
      gu += w * u_s[d]; gc += w * c1_s[d]; g0 += w * b2[d];
    }
    ws[S_GU + j] = gu; ws[S_GC + j] = gc;
    ws[S_G0 + j] = g0 + b_ih[j] + b_hh[j];
  }
}

// ---------------- graph structure ----------------
__global__ void k_zero(int* __restrict__ p, int n) {
  const int g = blockIdx.x * 256 + threadIdx.x;
  if (g < n) p[g] = 0;
}

__global__ void k_count(const int* __restrict__ edges, int* __restrict__ counts) {
  const int g = blockIdx.x * 256 + threadIdx.x;
  if (g >= NH * NE * NS) return;
  const int h = g >> 14;
  atomicAdd(&counts[h * NV + edges[g]], 1);
}

__global__ void k_scan(const int* __restrict__ counts, int* __restrict__ offs,
                       float* __restrict__ invdeg, float* __restrict__ mvec) {
  const int h = blockIdx.x;
  const int tid = threadIdx.x;  // 1024 threads
  const int base = h * NV;
  const int CH = 10;
  int local[10];
  int run = 0;
  for (int i = 0; i < CH; ++i) {
    const int v = tid * CH + i;
    const int c = (v < NV) ? counts[base + v] : 0;
    local[i] = run; run += c;
  }
  __shared__ int sd[1024];
  sd[tid] = run;
  __syncthreads();
  int acc = run;
  for (int off = 1; off < 1024; off <<= 1) {
    const int t = (tid >= off) ? sd[tid - off] : 0;
    __syncthreads();
    acc += t; sd[tid] = acc;
    __syncthreads();
  }
  const int excl = acc - run;
  for (int i = 0; i < CH; ++i) {
    const int v = tid * CH + i;
    if (v < NV) {
      offs[base + v] = excl + local[i];
      const int c = counts[base + v];
      invdeg[base + v] = 1.0f / (float)((c > 0) ? c : 1);
      mvec[base + v] = (c > 0) ? 1.0f : 0.0f;
    }
  }
}

__global__ void k_fill(const int* __restrict__ edges, const int* __restrict__ offs,
                       int* __restrict__ cursor, int* __restrict__ slot_edge) {
  const int g = blockIdx.x * 256 + threadIdx.x;
  if (g >= NH * NE * NS) return;
  const int h = g >> 14;
  const int e = (g >> 5) & (NE - 1);
  const int v = edges[g];
  const int pos = atomicAdd(&cursor[h * NV + v], 1);
  slot_edge[h * NE * NS + offs[h * NV + v] + pos] = e;
}

// ---------------- per-branch graph compute ----------------
__global__ void k_trans(const float* __restrict__ seq, float* __restrict__ xT) {
  __shared__ float tile[128][49];
  const int v0 = blockIdx.x * 128;
  const int tid = threadIdx.x;
  for (int i = tid; i < 128 * NSEQ; i += 256) {
    const int n = i / 128, vl = i % 128;
    const int v = v0 + vl;
    tile[vl][n] = (v < NV) ? seq[n * NV + v] : 0.0f;
  }
  __syncthreads();
  for (int i = tid; i < 128 * NSEQ; i += 256) {
    const int vl = i / NSEQ, n = i % NSEQ;
    const int v = v0 + vl;
    if (v < NV) xT[v * NSEQ + n] = tile[vl][n];
  }
}

__global__ void k_eagg1(const int* __restrict__ edges, const float* __restrict__ xT,
                        float* __restrict__ agg) {
  const int g = blockIdx.x * 256 + threadIdx.x;
  if (g >= NH * NE * NSEQ) return;
  const int n = g % NSEQ;
  const int e = (g / NSEQ) % NE;
  const int h = g / (NSEQ * NE);
  const int* ep = edges + (h * NE + e) * NS;
  float acc = 0.f;
  for (int s = 0; s < NS; ++s) acc += xT[ep[s] * NSEQ + n];
  agg[(h * NE + e) * NSEQ + n] = acc * (1.0f / NS);
}

__global__ void k_eagg2(const int* __restrict__ edges, const float* __restrict__ ysum,
                        const float* __restrict__ invdeg, float* __restrict__ agg) {
  const int g = blockIdx.x * 256 + threadIdx.x;
  if (g >= NH * NE * NSEQ) return;
  const int n = g % NSEQ;
  const int e = (g / NSEQ) % NE;
  const int h = g / (NSEQ * NE);
  const int* ep = edges + (h * NE + e) * NS;
  float acc = 0.f;
  for (int s = 0; s < NS; ++s) {
    const int v = ep[s];
    acc += ysum[(h * NV + v) * NSEQ + n] * invdeg[h * NV + v];
  }
  agg[(h * NE + e) * NSEQ + n] = acc * (1.0f / NS);
}

__global__ void k_vg(const int* __restrict__ counts, const int* __restrict__ offs,
                     const int* __restrict__ slot_edge, const float* __restrict__ agg,
                     float* __restrict__ outv) {
  const int g = blockIdx.x * 256 + threadIdx.x;
  if (g >= NH * NV * NSEQ) return;
  const int n = g % NSEQ;
  const int v = (g / NSEQ) % NV;
  const int h = g / (NSEQ * NV);
  const int beg = offs[h * NV + v];
  const int cnt = counts[h * NV + v];
  const int* se = slot_edge + h * NE * NS;
  float acc = 0.f;
  for (int i = 0; i < cnt; ++i) {
    const int e = se[beg + i];
    acc += agg[(h * NE + e) * NSEQ + n];
  }
  outv[(h * NV + v) * NSEQ + n] = acc;  // unnormalized (divide folded downstream)
}

__global__ void k_attn(const float* __restrict__ zsum, const float* __restrict__ invdeg,
                       const float* __restrict__ mvec, const float* __restrict__ ws,
                       float* __restrict__ pbuf, float* __restrict__ qbuf) {
  const int g = blockIdx.x * 256 + threadIdx.x;
  if (g >= NV * NSEQ) return;
  const int n = g % NSEQ;
  const int v = g / NSEQ;
  const float al = ws[S_SC + 0], be = ws[S_SC + 1], ga = ws[S_SC + 2],
              de = ws[S_SC + 3], ep = ws[S_SC + 4];
  float zh[3], mh[3];
  #pragma unroll
  for (int h = 0; h < NH; ++h) {
    zh[h] = zsum[(h * NV + v) * NSEQ + n] * invdeg[h * NV + v];
    mh[h] = mvec[h * NV + v];
  }
  const float zb = (zh[0] + zh[1] + zh[2]) * (1.f / 3.f);
  const float mb = (mh[0] + mh[1] + mh[2]) * (1.f / 3.f);
  float sc[3];
  #pragma unroll
  for (int h = 0; h < NH; ++h) {
    const float s = al * zh[h] + be * mh[h] + ga * zb + de * mb + ep;
    sc[h] = (s > 0.f) ? s : 0.2f * s;
  }
  const float mx = fmaxf(sc[0], fmaxf(sc[1], sc[2]));
  float e0 = __expf(sc[0] - mx), e1 = __expf(sc[1] - mx), e2 = __expf(sc[2] - mx);
  const float inv = 1.0f / (e0 + e1 + e2);
  pbuf[g] = (e0 * zh[0] + e1 * zh[1] + e2 * zh[2]) * inv;
  qbuf[g] = (e0 * mh[0] + e1 * mh[1] + e2 * mh[2]) * inv;
}

// ---------------- fused dual-branch LSTM + output ----------------
__launch_bounds__(256, 2)
__global__ void k_lstm(const float* __restrict__ w_hh, const float* __restrict__ ws,
                       const float* __restrict__ p0, const float* __restrict__ q0,
                       const float* __restrict__ p1, const float* __restrict__ q1,
                       const float* __restrict__ w_out, const float* __restrict__ b_out,
                       float* __restrict__ out) {
  __shared__ __align__(16) unsigned short w_sh[64 * 256];  // bf16, [k][j]
  __shared__ __align__(16) float h_sh[64 * 64];            // [s][k]
  const int tid = threadIdx.x;
  const int b = blockIdx.y;
  const int v0 = blockIdx.x * 64;
  // stage w_hh -> bf16 transposed
  for (int i = tid; i < 256 * 64; i += 256) {
    const int j = i >> 6, k = i & 63;
    unsigned int bits = __float_as_uint(w_hh[i]);
    bits = (bits + 0x7fffu + ((bits >> 16) & 1u)) >> 16;
    w_sh[k * 256 + j] = (unsigned short)bits;
  }
  const int sg = tid >> 4;  // seq group: 4 seqs
  const int dg = tid & 15;  // dim group: 4 dims
  float GU[4][4], GC[4][4], G0[4][4], WO0[4], WO1[4];
  #pragma unroll
  for (int g = 0; g < 4; ++g)
    #pragma unroll
    for (int r = 0; r < 4; ++r) {
      const int j = 64 * g + 4 * dg + r;
      GU[g][r] = ws[S_GU + j];
      GC[g][r] = ws[S_GC + j];
      G0[g][r] = ws[S_G0 + j];
    }
  #pragma unroll
  for (int r = 0; r < 4; ++r) {
    WO0[r] = w_out[4 * dg + r];
    WO1[r] = w_out[64 + 4 * dg + r];
  }
  const float bo = b_out[0];
  float part[4] = {0.f, 0.f, 0.f, 0.f};
  __syncthreads();  // w_sh ready
  #pragma unroll 1
  for (int br = 0; br < 2; ++br) {
    const float* __restrict__ pp = br ? p1 : p0;
    const float* __restrict__ qq = br ? q1 : q0;
    float c[4][4];
    #pragma unroll
    for (int i = 0; i < 4; ++i) {
      #pragma unroll
      for (int r = 0; r < 4; ++r) c[i][r] = 0.f;
      const float4 z4 = make_float4(0.f, 0.f, 0.f, 0.f);
      *(float4*)&h_sh[(sg * 4 + i) * 64 + 4 * dg] = z4;
    }
    __syncthreads();
    #pragma unroll 1
    for (int t = 0; t < NTT; ++t) {
      float acc[4][4][4];  // [gate][seq][dim]
      #pragma unroll
      for (int i = 0; i < 4; ++i) {
        const int v = v0 + sg * 4 + i;
        const bool ok = (v < NV);
        const int idx = v * NSEQ + b * NTT + t;
        const float pv = ok ? pp[idx] : 0.f;
        const float qv = ok ? qq[idx] : 0.f;
        #pragma unroll
        for (int g = 0; g < 4; ++g)
          #pragma unroll
          for (int r = 0; r < 4; ++r)
            acc[g][i][r] = fmaf(pv, GU[g][r], fmaf(qv, GC[g][r], G0[g][r]));
      }
      #pragma unroll 1
      for (int kc = 0; kc < 16; ++kc) {
        const int k0 = kc * 4;
        float4 hv[4];
        #pragma unroll
        for (int i = 0; i < 4; ++i)
          hv[i] = *(const float4*)&h_sh[(sg * 4 + i) * 64 + k0];
        #pragma unroll
        for (int kk = 0; kk < 4; ++kk) {
          #pragma unroll
          for (int g = 0; g < 4; ++g) {
            const uint2 wr = *(const uint2*)&w_sh[(k0 + kk) * 256 + 64 * g + 4 * dg];
            const float w0 = __uint_as_float(wr.x << 16);
            const float w1 = __uint_as_float(wr.x & 0xffff0000u);
            const float w2 = __uint_as_float(wr.y << 16);
            const float w3 = __uint_as_float(wr.y & 0xffff0000u);
            #pragma unroll
            for (int i = 0; i < 4; ++i) {
              const float hvv = (kk == 0) ? hv[i].x : (kk == 1) ? hv[i].y
                               : (kk == 2) ? hv[i].z : hv[i].w;
              acc[g][i][0] = fmaf(hvv, w0, acc[g][i][0]);
              acc[g][i][1] = fmaf(hvv, w1, acc[g][i][1]);
              acc[g][i][2] = fmaf(hvv, w2, acc[g][i][2]);
              acc[g][i][3] = fmaf(hvv, w3, acc[g][i][3]);
            }
          }
        }
      }
      __syncthreads();  // all h_sh reads done
      const bool last = (t == NTT - 1);
      #pragma unroll
      for (int i = 0; i < 4; ++i) {
        float hr[4];
        #pragma unroll
        for (int r = 0; r < 4; ++r) {
          const float ig = sigf(acc[0][i][r]);
          const float fg = sigf(acc[1][i][r]);
          const float gg = tanh_fast(acc[2][i][r]);
          const float og = sigf(acc[3][i][r]);
          const float cn = fmaf(fg, c[i][r], ig * gg);
          c[i][r] = cn;
          hr[r] = og * tanh_fast(cn);
        }
        float4 hnew;
        hnew.x = hr[0]; hnew.y = hr[1]; hnew.z = hr[2]; hnew.w = hr[3];
        *(float4*)&h_sh[(sg * 4 + i) * 64 + 4 * dg] = hnew;
        if (last) {
          #pragma unroll
          for (int r = 0; r < 4; ++r)
            part[i] = fmaf(hr[r], br ? WO1[r] : WO0[r], part[i]);
        }
      }
      __syncthreads();
    }
  }
  #pragma unroll
  for (int i = 0; i < 4; ++i)
    h_sh[(sg * 4 + i) * 16 + dg] = part[i];
  __syncthreads();
  if (tid < 64) {
    const int v = v0 + tid;
    float a = 0.f;
    #pragma unroll
    for (int d = 0; d < 16; ++d) a += h_sh[tid * 16 + d];
    if (v < NV) out[b * NV + v] = a + bo;
  }
}

extern "C" void kernel_launch(void* const* d_in, const int* in_sizes, int n_in,
                              void* d_out, int out_size, void* d_ws, size_t ws_size,
                              hipStream_t stream) {
  const float* tend   = (const float*)d_in[0];
  const float* peri   = (const float*)d_in[1];
  const int*   edges  = (const int*)d_in[2];
  const float* w1     = (const float*)d_in[3];
  const float* b1     = (const float*)d_in[4];
  const float* w2     = (const float*)d_in[5];
  const float* b2     = (const float*)d_in[6];
  const float* attn_w = (const float*)d_in[7];
  const float* attn_a = (const float*)d_in[8];
  const float* w_ih   = (const float*)d_in[9];
  const float* w_hh   = (const float*)d_in[10];
  const float* b_ih   = (const float*)d_in[11];
  const float* b_hh   = (const float*)d_in[12];
  const float* w_out  = (const float*)d_in[13];
  const float* b_out  = (const float*)d_in[14];
  float* out = (float*)d_out;
  float* ws  = (float*)d_ws;
  int*   iws = (int*)d_ws;
  int* cnt = iws + I_CNT;
  int* cur = iws + I_CUR;
  int* off = iws + I_OFF;
  int* sed = iws + I_SLOT;

  k_prep<<<1, 256, 0, stream>>>(w1, b1, w2, b2, attn_w, attn_a, w_ih, b_ih, b_hh, ws);
  k_zero<<<(2 * NH * NV + 255) / 256, 256, 0, stream>>>(cnt, 2 * NH * NV);
  k_count<<<(NH * NE * NS) / 256, 256, 0, stream>>>(edges, cnt);
  k_scan<<<NH, 1024, 0, stream>>>(cnt, off, ws + F_INV, ws + F_M);
  k_fill<<<(NH * NE * NS) / 256, 256, 0, stream>>>(edges, off, cur, sed);

  for (int br = 0; br < 2; ++br) {
    const float* seq = br ? peri : tend;
    float* pbuf = ws + (br ? F_P1 : F_P0);
    float* qbuf = ws + (br ? F_Q1 : F_Q0);
    k_trans<<<(NV + 127) / 128, 256, 0, stream>>>(seq, ws + F_XT);
    k_eagg1<<<(NH * NE * NSEQ) / 256, 256, 0, stream>>>(edges, ws + F_XT, ws + F_AGG);
    k_vg<<<(NH * NV * NSEQ) / 256, 256, 0, stream>>>(cnt, off, sed, ws + F_AGG, ws + F_Y);
    k_eagg2<<<(NH * NE * NSEQ) / 256, 256, 0, stream>>>(edges, ws + F_Y, ws + F_INV, ws + F_AGG);
    k_vg<<<(NH * NV * NSEQ) / 256, 256, 0, stream>>>(cnt, off, sed, ws + F_AGG, ws + F_Z);
    k_attn<<<(NV * NSEQ) / 256, 256, 0, stream>>>(ws + F_Z, ws + F_INV, ws + F_M, ws, pbuf, qbuf);
  }
  dim3 lgrid((NV + 63) / 64, NB);
  k_lstm<<<lgrid, 256, 0, stream>>>(w_hh, ws, ws + F_P0, ws + F_Q0, ws + F_P1, ws + F_Q1,
                                    w_out, b_out, out);
}

// Round 2
// 479.828 us; speedup vs baseline: 1.5617x; 1.5617x over previous
//
#include <hip/hip_runtime.h>

#define NV 10000
#define NB 4
#define NTT 12
#define NSEQ 48
#define NH 3
#define NE 512
#define NS 32
#define ND 64

// workspace layout (float indices)
#define S_U   0
#define S_C1  64
#define S_V1  128
#define S_V2  192
#define S_SC  256
#define S_GU  272
#define S_GC  528
#define S_G0  784
#define F_INV 1040
#define F_M   (F_INV + NH*NV)
#define F_XT  (F_M + NH*NV)
#define F_AGG (F_XT + NV*NSEQ)
#define F_Y   (F_AGG + NH*NE*NSEQ)
#define F_Z   (F_Y + NH*NV*NSEQ)
#define F_P0  (F_Z + NH*NV*NSEQ)
#define F_Q0  (F_P0 + NV*NSEQ)
#define F_P1  (F_Q0 + NV*NSEQ)
#define F_Q1  (F_P1 + NV*NSEQ)
#define F_HT  (F_Q1 + NV*NSEQ)
#define F_END (F_HT + 2*NB*NV)
// int region (int indices from ws base)
#define I_CNT  F_END
#define I_CUR  (I_CNT + NH*NV)
#define I_OFF  (I_CUR + NH*NV)
#define I_SLOT (I_OFF + NH*NV)

typedef __attribute__((ext_vector_type(8))) __bf16 bf16x8;
typedef __attribute__((ext_vector_type(4))) float f32x4;

__device__ __forceinline__ float sigf(float x) {
  return __builtin_amdgcn_rcpf(1.0f + __expf(-x));
}
__device__ __forceinline__ float tanh_fast(float x) {
  return 1.0f - 2.0f * __builtin_amdgcn_rcpf(1.0f + __expf(2.0f * x));
}
__device__ __forceinline__ unsigned short f2bf(float x) {
  unsigned int u = __float_as_uint(x);
  u = (u + 0x7fffu + ((u >> 16) & 1u)) >> 16;
  return (unsigned short)u;
}
__device__ __forceinline__ float bf2f(unsigned short h) {
  return __uint_as_float(((unsigned int)h) << 16);
}
__device__ __forceinline__ bf16x8 ldsA(const unsigned short* p) {
  union { uint4 u; bf16x8 v; } x;
  x.u = *(const uint4*)p;
  return x.v;
}

// ---------------- small weight precompute ----------------
__global__ void k_prep(const float* __restrict__ w1, const float* __restrict__ b1,
                       const float* __restrict__ w2, const float* __restrict__ b2,
                       const float* __restrict__ attn_w, const float* __restrict__ attn_a,
                       const float* __restrict__ w_ih, const float* __restrict__ b_ih,
                       const float* __restrict__ b_hh, float* __restrict__ ws) {
  __shared__ float u_s[64], c1_s[64];
  const int tid = threadIdx.x;
  if (tid < 64) {
    float v1 = 0.f, v2 = 0.f, u = 0.f, c1 = 0.f;
    for (int d = 0; d < 64; ++d) {
      const float aw = attn_w[tid * 64 + d];
      v1 += aw * attn_a[d];
      v2 += aw * attn_a[64 + d];
      const float w2v = w2[d * 64 + tid];
      u  += w1[d] * w2v;
      c1 += b1[d] * w2v;
    }
    ws[S_U + tid] = u;  ws[S_C1 + tid] = c1;
    ws[S_V1 + tid] = v1; ws[S_V2 + tid] = v2;
    u_s[tid] = u; c1_s[tid] = c1;
  }
  __syncthreads();
  if (tid == 0) {
    float al = 0.f, be = 0.f, ga = 0.f, de = 0.f, ep = 0.f;
    for (int d = 0; d < 64; ++d) {
      const float v1 = ws[S_V1 + d], v2 = ws[S_V2 + d];
      al += u_s[d] * v1;  be += c1_s[d] * v1;
      ga += u_s[d] * v2;  de += c1_s[d] * v2;
      ep += b2[d] * (v1 + v2);
    }
    ws[S_SC + 0] = al; ws[S_SC + 1] = be; ws[S_SC + 2] = ga;
    ws[S_SC + 3] = de; ws[S_SC + 4] = ep;
  }
  {
    const int j = tid;  // 256 threads exactly
    float gu = 0.f, gc = 0.f, g0 = 0.f;
    for (int d = 0; d < 64; ++d) {
      const float w = w_ih[j * 64 + d];
      gu += w * u_s[d]; gc += w * c1_s[d]; g0 += w * b2[d];
    }
    ws[S_GU + j] = gu; ws[S_GC + j] = gc;
    ws[S_G0 + j] = g0 + b_ih[j] + b_hh[j];
  }
}

// ---------------- graph structure ----------------
__global__ void k_zero(int* __restrict__ p, int n) {
  const int g = blockIdx.x * 256 + threadIdx.x;
  if (g < n) p[g] = 0;
}

__global__ void k_count(const int* __restrict__ edges, int* __restrict__ counts) {
  const int g = blockIdx.x * 256 + threadIdx.x;
  if (g >= NH * NE * NS) return;
  const int h = g >> 14;
  atomicAdd(&counts[h * NV + edges[g]], 1);
}

__global__ void k_scan(const int* __restrict__ counts, int* __restrict__ offs,
                       float* __restrict__ invdeg, float* __restrict__ mvec) {
  const int h = blockIdx.x;
  const int tid = threadIdx.x;  // 1024 threads
  const int base = h * NV;
  const int CH = 10;
  int local[10];
  int run = 0;
  for (int i = 0; i < CH; ++i) {
    const int v = tid * CH + i;
    const int c = (v < NV) ? counts[base + v] : 0;
    local[i] = run; run += c;
  }
  __shared__ int sd[1024];
  sd[tid] = run;
  __syncthreads();
  int acc = run;
  for (int off = 1; off < 1024; off <<= 1) {
    const int t = (tid >= off) ? sd[tid - off] : 0;
    __syncthreads();
    acc += t; sd[tid] = acc;
    __syncthreads();
  }
  const int excl = acc - run;
  for (int i = 0; i < CH; ++i) {
    const int v = tid * CH + i;
    if (v < NV) {
      offs[base + v] = excl + local[i];
      const int c = counts[base + v];
      invdeg[base + v] = 1.0f / (float)((c > 0) ? c : 1);
      mvec[base + v] = (c > 0) ? 1.0f : 0.0f;
    }
  }
}

__global__ void k_fill(const int* __restrict__ edges, const int* __restrict__ offs,
                       int* __restrict__ cursor, int* __restrict__ slot_edge) {
  const int g = blockIdx.x * 256 + threadIdx.x;
  if (g >= NH * NE * NS) return;
  const int h = g >> 14;
  const int e = (g >> 5) & (NE - 1);
  const int v = edges[g];
  const int pos = atomicAdd(&cursor[h * NV + v], 1);
  slot_edge[h * NE * NS + offs[h * NV + v] + pos] = e;
}

// ---------------- per-branch graph compute ----------------
__global__ void k_trans(const float* __restrict__ seq, float* __restrict__ xT) {
  __shared__ float tile[128][49];
  const int v0 = blockIdx.x * 128;
  const int tid = threadIdx.x;
  for (int i = tid; i < 128 * NSEQ; i += 256) {
    const int n = i / 128, vl = i % 128;
    const int v = v0 + vl;
    tile[vl][n] = (v < NV) ? seq[n * NV + v] : 0.0f;
  }
  __syncthreads();
  for (int i = tid; i < 128 * NSEQ; i += 256) {
    const int vl = i / NSEQ, n = i % NSEQ;
    const int v = v0 + vl;
    if (v < NV) xT[v * NSEQ + n] = tile[vl][n];
  }
}

__global__ void k_eagg1(const int* __restrict__ edges, const float* __restrict__ xT,
                        float* __restrict__ agg) {
  const int g = blockIdx.x * 256 + threadIdx.x;
  if (g >= NH * NE * NSEQ) return;
  const int n = g % NSEQ;
  const int e = (g / NSEQ) % NE;
  const int h = g / (NSEQ * NE);
  const int* ep = edges + (h * NE + e) * NS;
  float acc = 0.f;
  for (int s = 0; s < NS; ++s) acc += xT[ep[s] * NSEQ + n];
  agg[(h * NE + e) * NSEQ + n] = acc * (1.0f / NS);
}

__global__ void k_eagg2(const int* __restrict__ edges, const float* __restrict__ ysum,
                        const float* __restrict__ invdeg, float* __restrict__ agg) {
  const int g = blockIdx.x * 256 + threadIdx.x;
  if (g >= NH * NE * NSEQ) return;
  const int n = g % NSEQ;
  const int e = (g / NSEQ) % NE;
  const int h = g / (NSEQ * NE);
  const int* ep = edges + (h * NE + e) * NS;
  float acc = 0.f;
  for (int s = 0; s < NS; ++s) {
    const int v = ep[s];
    acc += ysum[(h * NV + v) * NSEQ + n] * invdeg[h * NV + v];
  }
  agg[(h * NE + e) * NSEQ + n] = acc * (1.0f / NS);
}

__global__ void k_vg(const int* __restrict__ counts, const int* __restrict__ offs,
                     const int* __restrict__ slot_edge, const float* __restrict__ agg,
                     float* __restrict__ outv) {
  const int g = blockIdx.x * 256 + threadIdx.x;
  if (g >= NH * NV * NSEQ) return;
  const int n = g % NSEQ;
  const int v = (g / NSEQ) % NV;
  const int h = g / (NSEQ * NV);
  const int beg = offs[h * NV + v];
  const int cnt = counts[h * NV + v];
  const int* se = slot_edge + h * NE * NS;
  float acc = 0.f;
  for (int i = 0; i < cnt; ++i) {
    const int e = se[beg + i];
    acc += agg[(h * NE + e) * NSEQ + n];
  }
  outv[(h * NV + v) * NSEQ + n] = acc;  // unnormalized (divide folded downstream)
}

__global__ void k_attn(const float* __restrict__ zsum, const float* __restrict__ invdeg,
                       const float* __restrict__ mvec, const float* __restrict__ ws,
                       float* __restrict__ pbuf, float* __restrict__ qbuf) {
  const int g = blockIdx.x * 256 + threadIdx.x;
  if (g >= NV * NSEQ) return;
  const int n = g % NSEQ;
  const int v = g / NSEQ;
  const float al = ws[S_SC + 0], be = ws[S_SC + 1], ga = ws[S_SC + 2],
              de = ws[S_SC + 3], ep = ws[S_SC + 4];
  float zh[3], mh[3];
  #pragma unroll
  for (int h = 0; h < NH; ++h) {
    zh[h] = zsum[(h * NV + v) * NSEQ + n] * invdeg[h * NV + v];
    mh[h] = mvec[h * NV + v];
  }
  const float zb = (zh[0] + zh[1] + zh[2]) * (1.f / 3.f);
  const float mb = (mh[0] + mh[1] + mh[2]) * (1.f / 3.f);
  float sc[3];
  #pragma unroll
  for (int h = 0; h < NH; ++h) {
    const float s = al * zh[h] + be * mh[h] + ga * zb + de * mb + ep;
    sc[h] = (s > 0.f) ? s : 0.2f * s;
  }
  const float mx = fmaxf(sc[0], fmaxf(sc[1], sc[2]));
  float e0 = __expf(sc[0] - mx), e1 = __expf(sc[1] - mx), e2 = __expf(sc[2] - mx);
  const float inv = 1.0f / (e0 + e1 + e2);
  pbuf[g] = (e0 * zh[0] + e1 * zh[1] + e2 * zh[2]) * inv;
  qbuf[g] = (e0 * mh[0] + e1 * mh[1] + e2 * mh[2]) * inv;
}

// ---------------- MFMA LSTM: one branch+batch per block.z/.y, 64 vertices per block.x ----
// Per block: 64 seqs, gates = xg + h @ w_hh^T via mfma_f32_16x16x32_bf16.
// h carried as split bf16 (hi+lo) -> fp32-accurate recurrence; w_hh single bf16.
#define RS 136  // LDS row stride in ushorts: 64 hi + 64 lo + 8 pad (bank shift 4/row)
__launch_bounds__(256, 3)
__global__ void k_lstm2(const float* __restrict__ w_hh, const float* __restrict__ ws,
                        const float* __restrict__ pbase, const float* __restrict__ w_out,
                        float* __restrict__ part) {
  __shared__ __align__(16) unsigned short hbuf[2][64 * RS];
  __shared__ float ps_sh[NTT][64], qs_sh[NTT][64];
  __shared__ float red_sh[64];
  const int tid = threadIdx.x;
  const int w = tid >> 6, lane = tid & 63, q = lane >> 4, l15 = lane & 15;
  const int b = blockIdx.y, br = blockIdx.z;
  const int v0 = blockIdx.x * 64;
  const int d = w * 16 + l15;  // this lane's gate-dim within [0,64)

  // B fragments: B[k][n=gate g*64+d], k = kh*32 + q*8 + j  (w_hh[gate][k])
  bf16x8 Bf[4][2];
  #pragma unroll
  for (int g = 0; g < 4; ++g)
    #pragma unroll
    for (int kh = 0; kh < 2; ++kh) {
      const float* src = w_hh + (g * 64 + d) * 64 + kh * 32 + q * 8;
      union { unsigned short s[8]; bf16x8 v; } u;
      #pragma unroll
      for (int j = 0; j < 8; ++j) u.s[j] = f2bf(src[j]);
      Bf[g][kh] = u.v;
    }

  float GUr[4], GCr[4], G0r[4];
  #pragma unroll
  for (int g = 0; g < 4; ++g) {
    GUr[g] = ws[S_GU + g * 64 + d];
    GCr[g] = ws[S_GC + g * 64 + d];
    G0r[g] = ws[S_G0 + g * 64 + d];
  }
  const float WO = w_out[br * 64 + d];

  // stage p,q for all 12 steps
  const float* pp = pbase + (size_t)br * 2 * NV * NSEQ;
  const float* qq = pp + NV * NSEQ;
  {
    const int s = tid >> 2, j0 = (tid & 3) * 3;
    const int v = v0 + s;
    #pragma unroll
    for (int j = 0; j < 3; ++j) {
      const int t = j0 + j;
      const int idx = v * NSEQ + b * NTT + t;
      ps_sh[t][s] = (v < NV) ? pp[idx] : 0.f;
      qs_sh[t][s] = (v < NV) ? qq[idx] : 0.f;
    }
  }
  if (tid < 64) red_sh[tid] = 0.f;
  __syncthreads();

  f32x4 acc[4][4];  // [mi seq-tile][g gate-type]
  f32x4 cst[4];
  #pragma unroll
  for (int mi = 0; mi < 4; ++mi) cst[mi] = (f32x4){0.f, 0.f, 0.f, 0.f};

  #pragma unroll 1
  for (int t = 0; t < NTT; ++t) {
    // input contribution: xg = p*GU + q*GC + G0 (D layout: row s=mi*16+q*4+r, col d)
    #pragma unroll
    for (int mi = 0; mi < 4; ++mi)
      #pragma unroll
      for (int r = 0; r < 4; ++r) {
        const int s = mi * 16 + q * 4 + r;
        const float pv = ps_sh[t][s], qv = qs_sh[t][s];
        #pragma unroll
        for (int g = 0; g < 4; ++g)
          acc[mi][g][r] = fmaf(pv, GUr[g], fmaf(qv, GCr[g], G0r[g]));
      }
    if (t > 0) {
      const int rb = (t - 1) & 1;
      #pragma unroll
      for (int kh = 0; kh < 2; ++kh)
        #pragma unroll
        for (int mi = 0; mi < 4; ++mi) {
          const int row = mi * 16 + l15;  // A layout: m = lane&15
          const int col = kh * 32 + q * 8;
          const bf16x8 Ahi = ldsA(&hbuf[rb][row * RS + col]);
          const bf16x8 Alo = ldsA(&hbuf[rb][row * RS + 64 + col]);
          #pragma unroll
          for (int g = 0; g < 4; ++g) {
            acc[mi][g] = __builtin_amdgcn_mfma_f32_16x16x32_bf16(Ahi, Bf[g][kh], acc[mi][g], 0, 0, 0);
            acc[mi][g] = __builtin_amdgcn_mfma_f32_16x16x32_bf16(Alo, Bf[g][kh], acc[mi][g], 0, 0, 0);
          }
        }
    }
    const int wb = t & 1;
    const bool last = (t == NTT - 1);
    #pragma unroll
    for (int mi = 0; mi < 4; ++mi)
      #pragma unroll
      for (int r = 0; r < 4; ++r) {
        const float ig = sigf(acc[mi][0][r]);
        const float fg = sigf(acc[mi][1][r]);
        const float gg = tanh_fast(acc[mi][2][r]);
        const float og = sigf(acc[mi][3][r]);
        const float cn = fmaf(fg, cst[mi][r], ig * gg);
        cst[mi][r] = cn;
        const float h = og * tanh_fast(cn);
        const int s = mi * 16 + q * 4 + r;
        if (!last) {
          const unsigned short hi = f2bf(h);
          const unsigned short lo = f2bf(h - bf2f(hi));
          hbuf[wb][s * RS + d] = hi;
          hbuf[wb][s * RS + 64 + d] = lo;
        } else {
          float v = h * WO;
          v += __shfl_xor(v, 1);
          v += __shfl_xor(v, 2);
          v += __shfl_xor(v, 4);
          v += __shfl_xor(v, 8);
          if (l15 == 0) atomicAdd(&red_sh[s], v);
        }
      }
    __syncthreads();
  }
  if (tid < 64) {
    const int v = v0 + tid;
    if (v < NV) part[(br * NB + b) * NV + v] = red_sh[tid];
  }
}

__global__ void k_comb(const float* __restrict__ part, const float* __restrict__ b_out,
                       float* __restrict__ out) {
  const int g = blockIdx.x * 256 + threadIdx.x;
  if (g >= NB * NV) return;
  out[g] = part[g] + part[NB * NV + g] + b_out[0];
}

extern "C" void kernel_launch(void* const* d_in, const int* in_sizes, int n_in,
                              void* d_out, int out_size, void* d_ws, size_t ws_size,
                              hipStream_t stream) {
  const float* tend   = (const float*)d_in[0];
  const float* peri   = (const float*)d_in[1];
  const int*   edges  = (const int*)d_in[2];
  const float* w1     = (const float*)d_in[3];
  const float* b1     = (const float*)d_in[4];
  const float* w2     = (const float*)d_in[5];
  const float* b2     = (const float*)d_in[6];
  const float* attn_w = (const float*)d_in[7];
  const float* attn_a = (const float*)d_in[8];
  const float* w_ih   = (const float*)d_in[9];
  const float* w_hh   = (const float*)d_in[10];
  const float* b_ih   = (const float*)d_in[11];
  const float* b_hh   = (const float*)d_in[12];
  const float* w_out  = (const float*)d_in[13];
  const float* b_out  = (const float*)d_in[14];
  float* out = (float*)d_out;
  float* ws  = (float*)d_ws;
  int*   iws = (int*)d_ws;
  int* cnt = iws + I_CNT;
  int* cur = iws + I_CUR;
  int* off = iws + I_OFF;
  int* sed = iws + I_SLOT;

  k_prep<<<1, 256, 0, stream>>>(w1, b1, w2, b2, attn_w, attn_a, w_ih, b_ih, b_hh, ws);
  k_zero<<<(2 * NH * NV + 255) / 256, 256, 0, stream>>>(cnt, 2 * NH * NV);
  k_count<<<(NH * NE * NS) / 256, 256, 0, stream>>>(edges, cnt);
  k_scan<<<NH, 1024, 0, stream>>>(cnt, off, ws + F_INV, ws + F_M);
  k_fill<<<(NH * NE * NS) / 256, 256, 0, stream>>>(edges, off, cur, sed);

  for (int br = 0; br < 2; ++br) {
    const float* seq = br ? peri : tend;
    float* pbuf = ws + (br ? F_P1 : F_P0);
    float* qbuf = ws + (br ? F_Q1 : F_Q0);
    k_trans<<<(NV + 127) / 128, 256, 0, stream>>>(seq, ws + F_XT);
    k_eagg1<<<(NH * NE * NSEQ) / 256, 256, 0, stream>>>(edges, ws + F_XT, ws + F_AGG);
    k_vg<<<(NH * NV * NSEQ) / 256, 256, 0, stream>>>(cnt, off, sed, ws + F_AGG, ws + F_Y);
    k_eagg2<<<(NH * NE * NSEQ) / 256, 256, 0, stream>>>(edges, ws + F_Y, ws + F_INV, ws + F_AGG);
    k_vg<<<(NH * NV * NSEQ) / 256, 256, 0, stream>>>(cnt, off, sed, ws + F_AGG, ws + F_Z);
    k_attn<<<(NV * NSEQ) / 256, 256, 0, stream>>>(ws + F_Z, ws + F_INV, ws + F_M, ws, pbuf, qbuf);
  }
  dim3 lgrid((NV + 63) / 64, NB, 2);
  k_lstm2<<<lgrid, 256, 0, stream>>>(w_hh, ws, ws + F_P0, w_out, ws + F_HT);
  k_comb<<<(NB * NV + 255) / 256, 256, 0, stream>>>(ws + F_HT, b_out, out);
}

// Round 4
// 310.265 us; speedup vs baseline: 2.4152x; 1.5465x over previous
//
#include <hip/hip_runtime.h>

#define NV 10000
#define NB 4
#define NTT 12
#define NSEQ 48
#define NH 3
#define NE 512
#define NS 32
#define ND 64

// ---- fixed workspace layout (element indices; float and int regions share the base) ----
#define S_U   0
#define S_C1  64
#define S_V1  128
#define S_V2  192
#define S_SC  256
#define S_GU  272
#define S_GC  528
#define S_G0  784
#define F_INV 1040
#define F_M   (F_INV + NH*NV)            // 31040
#define F_PQ  (F_M + NH*NV)              // 61040  (4 x NV*NSEQ: p0,q0,p1,q1)
#define F_HT  (F_PQ + 4*NV*NSEQ)         // 1981040 (2*NB*NV partials)
#define I_CNT (F_HT + 2*NB*NV)           // 2061040
#define I_CUR (I_CNT + NH*NV)
#define I_OFF (I_CUR + NH*NV)
#define I_SLOT (I_OFF + NH*NV)
#define F_DYN (I_SLOT + NH*NE*NS)        // 2200192
#define XT_SZ  (NV*NSEQ)                 // 480000
#define AGG_SZ (NH*NE*NSEQ)              // 73728
#define YZ_SZ  (NH*NV*NSEQ)              // 1440000

typedef __attribute__((ext_vector_type(8))) __bf16 bf16x8;
typedef __attribute__((ext_vector_type(4))) float f32x4;

__device__ __forceinline__ float sigf(float x) {
  return __builtin_amdgcn_rcpf(1.0f + __expf(-x));
}
__device__ __forceinline__ float tanh_fast(float x) {
  return 1.0f - 2.0f * __builtin_amdgcn_rcpf(1.0f + __expf(2.0f * x));
}
__device__ __forceinline__ unsigned short f2bf(float x) {
  unsigned int u = __float_as_uint(x);
  u = (u + 0x7fffu + ((u >> 16) & 1u)) >> 16;
  return (unsigned short)u;
}
__device__ __forceinline__ float bf2f(unsigned short h) {
  return __uint_as_float(((unsigned int)h) << 16);
}
__device__ __forceinline__ bf16x8 ldsA(const unsigned short* p) {
  union { uint4 u; bf16x8 v; } x;
  x.u = *(const uint4*)p;
  return x.v;
}

// ---------------- small weight precompute ----------------
__global__ void k_prep(const float* __restrict__ w1, const float* __restrict__ b1,
                       const float* __restrict__ w2, const float* __restrict__ b2,
                       const float* __restrict__ attn_w, const float* __restrict__ attn_a,
                       const float* __restrict__ w_ih, const float* __restrict__ b_ih,
                       const float* __restrict__ b_hh, float* __restrict__ ws) {
  __shared__ float u_s[64], c1_s[64];
  const int tid = threadIdx.x;
  if (tid < 64) {
    float v1 = 0.f, v2 = 0.f, u = 0.f, c1 = 0.f;
    for (int d = 0; d < 64; ++d) {
      const float aw = attn_w[tid * 64 + d];
      v1 += aw * attn_a[d];
      v2 += aw * attn_a[64 + d];
      const float w2v = w2[d * 64 + tid];
      u  += w1[d] * w2v;
      c1 += b1[d] * w2v;
    }
    ws[S_U + tid] = u;  ws[S_C1 + tid] = c1;
    ws[S_V1 + tid] = v1; ws[S_V2 + tid] = v2;
    u_s[tid] = u; c1_s[tid] = c1;
  }
  __syncthreads();
  if (tid == 0) {
    float al = 0.f, be = 0.f, ga = 0.f, de = 0.f, ep = 0.f;
    for (int d = 0; d < 64; ++d) {
      const float v1 = ws[S_V1 + d], v2 = ws[S_V2 + d];
      al += u_s[d] * v1;  be += c1_s[d] * v1;
      ga += u_s[d] * v2;  de += c1_s[d] * v2;
      ep += b2[d] * (v1 + v2);
    }
    ws[S_SC + 0] = al; ws[S_SC + 1] = be; ws[S_SC + 2] = ga;
    ws[S_SC + 3] = de; ws[S_SC + 4] = ep;
  }
  {
    const int j = tid;  // 256 threads exactly
    float gu = 0.f, gc = 0.f, g0 = 0.f;
    for (int d = 0; d < 64; ++d) {
      const float w = w_ih[j * 64 + d];
      gu += w * u_s[d]; gc += w * c1_s[d]; g0 += w * b2[d];
    }
    ws[S_GU + j] = gu; ws[S_GC + j] = gc;
    ws[S_G0 + j] = g0 + b_ih[j] + b_hh[j];
  }
}

// ---------------- graph structure ----------------
__global__ void k_zero(int* __restrict__ p, int n) {
  const int g = blockIdx.x * 256 + threadIdx.x;
  if (g < n) p[g] = 0;
}

__global__ void k_count(const int* __restrict__ edges, int* __restrict__ counts) {
  const int g = blockIdx.x * 256 + threadIdx.x;
  if (g >= NH * NE * NS) return;
  const int h = g >> 14;
  atomicAdd(&counts[h * NV + edges[g]], 1);
}

__global__ void k_scan(const int* __restrict__ counts, int* __restrict__ offs,
                       float* __restrict__ invdeg, float* __restrict__ mvec) {
  const int h = blockIdx.x;
  const int tid = threadIdx.x;  // 1024 threads
  const int base = h * NV;
  const int CH = 10;
  int local[10];
  int run = 0;
  for (int i = 0; i < CH; ++i) {
    const int v = tid * CH + i;
    const int c = (v < NV) ? counts[base + v] : 0;
    local[i] = run; run += c;
  }
  __shared__ int sd[1024];
  sd[tid] = run;
  __syncthreads();
  int acc = run;
  for (int off = 1; off < 1024; off <<= 1) {
    const int t = (tid >= off) ? sd[tid - off] : 0;
    __syncthreads();
    acc += t; sd[tid] = acc;
    __syncthreads();
  }
  const int excl = acc - run;
  for (int i = 0; i < CH; ++i) {
    const int v = tid * CH + i;
    if (v < NV) {
      offs[base + v] = excl + local[i];
      const int c = counts[base + v];
      invdeg[base + v] = 1.0f / (float)((c > 0) ? c : 1);
      mvec[base + v] = (c > 0) ? 1.0f : 0.0f;
    }
  }
}

__global__ void k_fill(const int* __restrict__ edges, const int* __restrict__ offs,
                       int* __restrict__ cursor, int* __restrict__ slot_edge) {
  const int g = blockIdx.x * 256 + threadIdx.x;
  if (g >= NH * NE * NS) return;
  const int h = g >> 14;
  const int e = (g >> 5) & (NE - 1);
  const int v = edges[g];
  const int pos = atomicAdd(&cursor[h * NV + v], 1);
  slot_edge[h * NE * NS + offs[h * NV + v] + pos] = e;
}

// ---------------- per-branch graph compute (branch = blockIdx.y) ----------------
__global__ void k_trans2(const float* __restrict__ s0, const float* __restrict__ s1,
                         float* __restrict__ xT, int xtS) {
  __shared__ float tile[128][49];
  const float* seq = blockIdx.y ? s1 : s0;
  float* o = xT + (size_t)blockIdx.y * xtS;
  const int v0 = blockIdx.x * 128;
  const int tid = threadIdx.x;
  for (int i = tid; i < 128 * NSEQ; i += 256) {
    const int n = i / 128, vl = i % 128;
    const int v = v0 + vl;
    tile[vl][n] = (v < NV) ? seq[n * NV + v] : 0.0f;
  }
  __syncthreads();
  for (int i = tid; i < 128 * NSEQ; i += 256) {
    const int vl = i / NSEQ, n = i % NSEQ;
    const int v = v0 + vl;
    if (v < NV) o[v * NSEQ + n] = tile[vl][n];
  }
}

__global__ void k_eagg1(const int* __restrict__ edges, const float* __restrict__ xT,
                        int xtS, float* __restrict__ agg, int aggS) {
  const int g = blockIdx.x * 256 + threadIdx.x;
  if (g >= NH * NE * NSEQ) return;
  const float* x = xT + (size_t)blockIdx.y * xtS;
  float* a = agg + (size_t)blockIdx.y * aggS;
  const int n = g % NSEQ;
  const int e = (g / NSEQ) % NE;
  const int h = g / (NSEQ * NE);
  const int* ep = edges + (h * NE + e) * NS;
  float acc = 0.f;
  for (int s = 0; s < NS; ++s) acc += x[ep[s] * NSEQ + n];
  a[(h * NE + e) * NSEQ + n] = acc * (1.0f / NS);
}

__global__ void k_eagg2(const int* __restrict__ edges, const float* __restrict__ ysum,
                        int yS, const float* __restrict__ invdeg,
                        float* __restrict__ agg, int aggS) {
  const int g = blockIdx.x * 256 + threadIdx.x;
  if (g >= NH * NE * NSEQ) return;
  const float* y = ysum + (size_t)blockIdx.y * yS;
  float* a = agg + (size_t)blockIdx.y * aggS;
  const int n = g % NSEQ;
  const int e = (g / NSEQ) % NE;
  const int h = g / (NSEQ * NE);
  const int* ep = edges + (h * NE + e) * NS;
  float acc = 0.f;
  for (int s = 0; s < NS; ++s) {
    const int v = ep[s];
    acc += y[(h * NV + v) * NSEQ + n] * invdeg[h * NV + v];
  }
  a[(h * NE + e) * NSEQ + n] = acc * (1.0f / NS);
}

__global__ void k_vg(const int* __restrict__ counts, const int* __restrict__ offs,
                     const int* __restrict__ slot_edge, const float* __restrict__ agg,
                     int aggS, float* __restrict__ outv, int outS) {
  const int g = blockIdx.x * 256 + threadIdx.x;
  if (g >= NH * NV * NSEQ) return;
  const float* a = agg + (size_t)blockIdx.y * aggS;
  float* o = outv + (size_t)blockIdx.y * outS;
  const int n = g % NSEQ;
  const int v = (g / NSEQ) % NV;
  const int h = g / (NSEQ * NV);
  const int beg = offs[h * NV + v];
  const int cnt = counts[h * NV + v];
  const int* se = slot_edge + h * NE * NS;
  float acc = 0.f;
  for (int i = 0; i < cnt; ++i) {
    const int e = se[beg + i];
    acc += a[(h * NE + e) * NSEQ + n];
  }
  o[(h * NV + v) * NSEQ + n] = acc;  // unnormalized (divide folded downstream)
}

__global__ void k_attn(const float* __restrict__ zsum, int zS,
                       const float* __restrict__ invdeg, const float* __restrict__ mvec,
                       const float* __restrict__ ws, float* __restrict__ pq, int br0) {
  const int g = blockIdx.x * 256 + threadIdx.x;
  if (g >= NV * NSEQ) return;
  const int bi = blockIdx.y;
  const float* z = zsum + (size_t)bi * zS;
  float* pbuf = pq + (size_t)(bi + br0) * 2 * NV * NSEQ;
  float* qbuf = pbuf + NV * NSEQ;
  const int n = g % NSEQ;
  const int v = g / NSEQ;
  const float al = ws[S_SC + 0], be = ws[S_SC + 1], ga = ws[S_SC + 2],
              de = ws[S_SC + 3], ep = ws[S_SC + 4];
  float zh[3], mh[3];
  #pragma unroll
  for (int h = 0; h < NH; ++h) {
    zh[h] = z[(h * NV + v) * NSEQ + n] * invdeg[h * NV + v];
    mh[h] = mvec[h * NV + v];
  }
  const float zb = (zh[0] + zh[1] + zh[2]) * (1.f / 3.f);
  const float mb = (mh[0] + mh[1] + mh[2]) * (1.f / 3.f);
  float sc[3];
  #pragma unroll
  for (int h = 0; h < NH; ++h) {
    const float s = al * zh[h] + be * mh[h] + ga * zb + de * mb + ep;
    sc[h] = (s > 0.f) ? s : 0.2f * s;
  }
  const float mx = fmaxf(sc[0], fmaxf(sc[1], sc[2]));
  float e0 = __expf(sc[0] - mx), e1 = __expf(sc[1] - mx), e2 = __expf(sc[2] - mx);
  const float inv = 1.0f / (e0 + e1 + e2);
  pbuf[g] = (e0 * zh[0] + e1 * zh[1] + e2 * zh[2]) * inv;
  qbuf[g] = (e0 * mh[0] + e1 * mh[1] + e2 * mh[2]) * inv;
}

// ---------------- MFMA LSTM ----------------
// Block: 64 vertices (seqs), batch b = blockIdx.y, branch = blockIdx.z.
// gates = xg + h @ w_hh^T via mfma_f32_16x16x32_bf16; h carried as split bf16 hi+lo.
// w_hh staged once, coalesced, into LDS (bf16); same LDS region is then reused as
// the h double-buffer (w fragments live in registers for all 12 steps).
#define RSW 72   // w-stage row stride (ushorts): 64 + 8 pad, 144 B (16B-aligned rows)
#define RS  136  // h row stride (ushorts): 64 hi + 64 lo + 8 pad, 272 B (16B-aligned)
__launch_bounds__(256, 2)
__global__ void k_lstm2(const float* __restrict__ w_hh, const float* __restrict__ ws,
                        const float* __restrict__ pbase, const float* __restrict__ w_out,
                        float* __restrict__ part) {
  __shared__ __align__(16) unsigned short smem[256 * RSW];  // 36864 B; w stage, then h dbuf (2*64*RS=17408 ush)
  __shared__ float ps_sh[NTT][64], qs_sh[NTT][64];
  __shared__ float red_sh[64];
  const int tid = threadIdx.x;
  const int w = tid >> 6, lane = tid & 63, q = lane >> 4, l15 = lane & 15;
  const int b = blockIdx.y, br = blockIdx.z;
  const int v0 = blockIdx.x * 64;
  const int d = w * 16 + l15;  // this lane's gate-dim within [0,64)

  // coalesced stage: w_hh fp32 [256][64] -> smem bf16 [j][RSW]
  for (int i = tid; i < 4096; i += 256) {
    const float4 w4 = ((const float4*)w_hh)[i];
    const int j = i >> 4, k = (i & 15) * 4;
    uint2 pk;
    pk.x = (unsigned int)f2bf(w4.x) | ((unsigned int)f2bf(w4.y) << 16);
    pk.y = (unsigned int)f2bf(w4.z) | ((unsigned int)f2bf(w4.w) << 16);
    *(uint2*)&smem[j * RSW + k] = pk;
  }
  // stage p,q for all 12 steps (float4 over t)
  const float* pp = pbase + (size_t)br * 2 * NV * NSEQ;
  const float* qq = pp + NV * NSEQ;
  for (int i = tid; i < 384; i += 256) {
    const int arr = (i >= 192) ? 1 : 0;
    const int ii = i - arr * 192;
    const int s = ii / 3, f4 = ii % 3;
    const int v = v0 + s;
    const float* src = arr ? qq : pp;
    float4 val = make_float4(0.f, 0.f, 0.f, 0.f);
    if (v < NV) val = *(const float4*)&src[v * NSEQ + b * NTT + f4 * 4];
    float (*dst)[64] = arr ? qs_sh : ps_sh;
    dst[f4 * 4 + 0][s] = val.x; dst[f4 * 4 + 1][s] = val.y;
    dst[f4 * 4 + 2][s] = val.z; dst[f4 * 4 + 3][s] = val.w;
  }
  if (tid < 64) red_sh[tid] = 0.f;
  __syncthreads();

  // B fragments from LDS: B[k][n=gate g*64+d], k = kh*32 + q*8 + j
  bf16x8 Bf[4][2];
  #pragma unroll
  for (int g = 0; g < 4; ++g)
    #pragma unroll
    for (int kh = 0; kh < 2; ++kh)
      Bf[g][kh] = ldsA(&smem[(g * 64 + d) * RSW + kh * 32 + q * 8]);

  float GUr[4], GCr[4], G0r[4];
  #pragma unroll
  for (int g = 0; g < 4; ++g) {
    GUr[g] = ws[S_GU + g * 64 + d];
    GCr[g] = ws[S_GC + g * 64 + d];
    G0r[g] = ws[S_G0 + g * 64 + d];
  }
  const float WO = w_out[br * 64 + d];
  __syncthreads();  // all waves done reading w-stage; reuse smem as h dbuf

  f32x4 acc[4][4];  // [mi seq-tile][g gate-type]
  f32x4 cst[4];
  #pragma unroll
  for (int mi = 0; mi < 4; ++mi) cst[mi] = (f32x4){0.f, 0.f, 0.f, 0.f};

  #pragma unroll 1
  for (int t = 0; t < NTT; ++t) {
    // input contribution: xg = p*GU + q*GC + G0 (D layout: row s=mi*16+q*4+r, col d)
    #pragma unroll
    for (int mi = 0; mi < 4; ++mi)
      #pragma unroll
      for (int r = 0; r < 4; ++r) {
        const int s = mi * 16 + q * 4 + r;
        const float pv = ps_sh[t][s], qv = qs_sh[t][s];
        #pragma unroll
        for (int g = 0; g < 4; ++g)
          acc[mi][g][r] = fmaf(pv, GUr[g], fmaf(qv, GCr[g], G0r[g]));
      }
    if (t > 0) {
      const unsigned short* hr = smem + ((t - 1) & 1) * (64 * RS);
      #pragma unroll
      for (int kh = 0; kh < 2; ++kh)
        #pragma unroll
        for (int mi = 0; mi < 4; ++mi) {
          const int row = mi * 16 + l15;  // A layout: m = lane&15
          const int col = kh * 32 + q * 8;
          const bf16x8 Ahi = ldsA(&hr[row * RS + col]);
          const bf16x8 Alo = ldsA(&hr[row * RS + 64 + col]);
          #pragma unroll
          for (int g = 0; g < 4; ++g) {
            acc[mi][g] = __builtin_amdgcn_mfma_f32_16x16x32_bf16(Ahi, Bf[g][kh], acc[mi][g], 0, 0, 0);
            acc[mi][g] = __builtin_amdgcn_mfma_f32_16x16x32_bf16(Alo, Bf[g][kh], acc[mi][g], 0, 0, 0);
          }
        }
    }
    unsigned short* hw = smem + (t & 1) * (64 * RS);
    const bool last = (t == NTT - 1);
    #pragma unroll
    for (int mi = 0; mi < 4; ++mi)
      #pragma unroll
      for (int r = 0; r < 4; ++r) {
        const float ig = sigf(acc[mi][0][r]);
        const float fg = sigf(acc[mi][1][r]);
        const float gg = tanh_fast(acc[mi][2][r]);
        const float og = sigf(acc[mi][3][r]);
        const float cn = fmaf(fg, cst[mi][r], ig * gg);
        cst[mi][r] = cn;
        const float h = og * tanh_fast(cn);
        const int s = mi * 16 + q * 4 + r;
        if (!last) {
          const unsigned short hi = f2bf(h);
          const unsigned short lo = f2bf(h - bf2f(hi));
          hw[s * RS + d] = hi;
          hw[s * RS + 64 + d] = lo;
        } else {
          float v = h * WO;
          v += __shfl_xor(v, 1);
          v += __shfl_xor(v, 2);
          v += __shfl_xor(v, 4);
          v += __shfl_xor(v, 8);
          if (l15 == 0) atomicAdd(&red_sh[s], v);
        }
      }
    __syncthreads();
  }
  if (tid < 64) {
    const int v = v0 + tid;
    if (v < NV) part[(br * NB + b) * NV + v] = red_sh[tid];
  }
}

__global__ void k_comb(const float* __restrict__ part, const float* __restrict__ b_out,
                       float* __restrict__ out) {
  const int g = blockIdx.x * 256 + threadIdx.x;
  if (g >= NB * NV) return;
  out[g] = part[g] + part[NB * NV + g] + b_out[0];
}

extern "C" void kernel_launch(void* const* d_in, const int* in_sizes, int n_in,
                              void* d_out, int out_size, void* d_ws, size_t ws_size,
                              hipStream_t stream) {
  const float* tend   = (const float*)d_in[0];
  const float* peri   = (const float*)d_in[1];
  const int*   edges  = (const int*)d_in[2];
  const float* w1     = (const float*)d_in[3];
  const float* b1     = (const float*)d_in[4];
  const float* w2     = (const float*)d_in[5];
  const float* b2     = (const float*)d_in[6];
  const float* attn_w = (const float*)d_in[7];
  const float* attn_a = (const float*)d_in[8];
  const float* w_ih   = (const float*)d_in[9];
  const float* w_hh   = (const float*)d_in[10];
  const float* b_ih   = (const float*)d_in[11];
  const float* b_hh   = (const float*)d_in[12];
  const float* w_out  = (const float*)d_in[13];
  const float* b_out  = (const float*)d_in[14];
  float* out = (float*)d_out;
  float* ws  = (float*)d_ws;
  int*   iws = (int*)d_ws;
  int* cnt = iws + I_CNT;
  int* cur = iws + I_CUR;
  int* off = iws + I_OFF;
  int* sed = iws + I_SLOT;

  const size_t need2 = ((size_t)F_DYN + 2 * (XT_SZ + AGG_SZ + YZ_SZ)) * 4;
  const bool batched = ws_size >= need2;
  const int nb = batched ? 2 : 1;
  float* XT  = ws + F_DYN;
  float* AGG = XT + (size_t)nb * XT_SZ;
  float* YZ  = AGG + (size_t)nb * AGG_SZ;

  k_prep<<<1, 256, 0, stream>>>(w1, b1, w2, b2, attn_w, attn_a, w_ih, b_ih, b_hh, ws);
  k_zero<<<(2 * NH * NV + 255) / 256, 256, 0, stream>>>(cnt, 2 * NH * NV);
  k_count<<<(NH * NE * NS) / 256, 256, 0, stream>>>(edges, cnt);
  k_scan<<<NH, 1024, 0, stream>>>(cnt, off, ws + F_INV, ws + F_M);
  k_fill<<<(NH * NE * NS) / 256, 256, 0, stream>>>(edges, off, cur, sed);

  if (batched) {
    k_trans2<<<dim3((NV + 127) / 128, 2), 256, 0, stream>>>(tend, peri, XT, XT_SZ);
    k_eagg1<<<dim3(NH * NE * NSEQ / 256, 2), 256, 0, stream>>>(edges, XT, XT_SZ, AGG, AGG_SZ);
    k_vg<<<dim3(NH * NV * NSEQ / 256, 2), 256, 0, stream>>>(cnt, off, sed, AGG, AGG_SZ, YZ, YZ_SZ);
    k_eagg2<<<dim3(NH * NE * NSEQ / 256, 2), 256, 0, stream>>>(edges, YZ, YZ_SZ, ws + F_INV, AGG, AGG_SZ);
    k_vg<<<dim3(NH * NV * NSEQ / 256, 2), 256, 0, stream>>>(cnt, off, sed, AGG, AGG_SZ, YZ, YZ_SZ);
    k_attn<<<dim3(NV * NSEQ / 256, 2), 256, 0, stream>>>(YZ, YZ_SZ, ws + F_INV, ws + F_M, ws, ws + F_PQ, 0);
  } else {
    for (int br = 0; br < 2; ++br) {
      const float* seq = br ? peri : tend;
      k_trans2<<<dim3((NV + 127) / 128, 1), 256, 0, stream>>>(seq, seq, XT, 0);
      k_eagg1<<<dim3(NH * NE * NSEQ / 256, 1), 256, 0, stream>>>(edges, XT, 0, AGG, 0);
      k_vg<<<dim3(NH * NV * NSEQ / 256, 1), 256, 0, stream>>>(cnt, off, sed, AGG, 0, YZ, 0);
      k_eagg2<<<dim3(NH * NE * NSEQ / 256, 1), 256, 0, stream>>>(edges, YZ, 0, ws + F_INV, AGG, 0);
      k_vg<<<dim3(NH * NV * NSEQ / 256, 1), 256, 0, stream>>>(cnt, off, sed, AGG, 0, YZ, 0);
      k_attn<<<dim3(NV * NSEQ / 256, 1), 256, 0, stream>>>(YZ, 0, ws + F_INV, ws + F_M, ws, ws + F_PQ, br);
    }
  }
  dim3 lgrid((NV + 63) / 64, NB, 2);
  k_lstm2<<<lgrid, 256, 0, stream>>>(w_hh, ws, ws + F_PQ, w_out, ws + F_HT);
  k_comb<<<(NB * NV + 255) / 256, 256, 0, stream>>>(ws + F_HT, b_out, out);
}

// Round 5
// 291.054 us; speedup vs baseline: 2.5746x; 1.0660x over previous
//
#include <hip/hip_runtime.h>

#define NV 10000
#define NB 4
#define NTT 12
#define NSEQ 48
#define NH 3
#define NE 512
#define NS 32
#define ND 64

// ---- fixed workspace layout (element indices; float and int regions share the base) ----
#define S_U   0
#define S_C1  64
#define S_V1  128
#define S_V2  192
#define S_SC  256
#define S_GU  272
#define S_GC  528
#define S_G0  784
#define F_INV 1040
#define F_M   (F_INV + NH*NV)            // 31040
#define F_PQ  (F_M + NH*NV)              // 61040  (4 x NV*NSEQ: p0,q0,p1,q1)
#define F_HT  (F_PQ + 4*NV*NSEQ)         // 1981040 (2*NB*NV partials)
#define I_CNT (F_HT + 2*NB*NV)           // 2061040
#define I_CUR (I_CNT + NH*NV)
#define I_OFF (I_CUR + NH*NV)
#define I_SLOT (I_OFF + NH*NV)
#define F_DYN (I_SLOT + NH*NE*NS)        // 2200192
#define XT_SZ  (NV*NSEQ)                 // 480000
#define AGG_SZ (NH*NE*NSEQ)              // 73728
#define YZ_SZ  (NH*NV*NSEQ)              // 1440000

typedef __attribute__((ext_vector_type(8))) __bf16 bf16x8;
typedef __attribute__((ext_vector_type(4))) float f32x4;

__device__ __forceinline__ float sigf(float x) {
  return __builtin_amdgcn_rcpf(1.0f + __expf(-x));
}
__device__ __forceinline__ float tanh_fast(float x) {
  return 1.0f - 2.0f * __builtin_amdgcn_rcpf(1.0f + __expf(2.0f * x));
}
__device__ __forceinline__ unsigned short f2bf(float x) {
  unsigned int u = __float_as_uint(x);
  u = (u + 0x7fffu + ((u >> 16) & 1u)) >> 16;
  return (unsigned short)u;
}
__device__ __forceinline__ float bf2f(unsigned short h) {
  return __uint_as_float(((unsigned int)h) << 16);
}
__device__ __forceinline__ bf16x8 ldsA(const unsigned short* p) {
  union { uint4 u; bf16x8 v; } x;
  x.u = *(const uint4*)p;
  return x.v;
}

// ---------------- small weight precompute ----------------
__global__ void k_prep(const float* __restrict__ w1, const float* __restrict__ b1,
                       const float* __restrict__ w2, const float* __restrict__ b2,
                       const float* __restrict__ attn_w, const float* __restrict__ attn_a,
                       const float* __restrict__ w_ih, const float* __restrict__ b_ih,
                       const float* __restrict__ b_hh, float* __restrict__ ws) {
  __shared__ float u_s[64], c1_s[64];
  const int tid = threadIdx.x;
  if (tid < 64) {
    float v1 = 0.f, v2 = 0.f, u = 0.f, c1 = 0.f;
    for (int d = 0; d < 64; ++d) {
      const float aw = attn_w[tid * 64 + d];
      v1 += aw * attn_a[d];
      v2 += aw * attn_a[64 + d];
      const float w2v = w2[d * 64 + tid];
      u  += w1[d] * w2v;
      c1 += b1[d] * w2v;
    }
    ws[S_U + tid] = u;  ws[S_C1 + tid] = c1;
    ws[S_V1 + tid] = v1; ws[S_V2 + tid] = v2;
    u_s[tid] = u; c1_s[tid] = c1;
  }
  __syncthreads();
  if (tid == 0) {
    float al = 0.f, be = 0.f, ga = 0.f, de = 0.f, ep = 0.f;
    for (int d = 0; d < 64; ++d) {
      const float v1 = ws[S_V1 + d], v2 = ws[S_V2 + d];
      al += u_s[d] * v1;  be += c1_s[d] * v1;
      ga += u_s[d] * v2;  de += c1_s[d] * v2;
      ep += b2[d] * (v1 + v2);
    }
    ws[S_SC + 0] = al; ws[S_SC + 1] = be; ws[S_SC + 2] = ga;
    ws[S_SC + 3] = de; ws[S_SC + 4] = ep;
  }
  {
    const int j = tid;  // 256 threads exactly
    float gu = 0.f, gc = 0.f, g0 = 0.f;
    for (int d = 0; d < 64; ++d) {
      const float w = w_ih[j * 64 + d];
      gu += w * u_s[d]; gc += w * c1_s[d]; g0 += w * b2[d];
    }
    ws[S_GU + j] = gu; ws[S_GC + j] = gc;
    ws[S_G0 + j] = g0 + b_ih[j] + b_hh[j];
  }
}

// ---------------- graph structure ----------------
__global__ void k_zero(int* __restrict__ p, int n) {
  const int g = blockIdx.x * 256 + threadIdx.x;
  if (g < n) p[g] = 0;
}

__global__ void k_count(const int* __restrict__ edges, int* __restrict__ counts) {
  const int g = blockIdx.x * 256 + threadIdx.x;
  if (g >= NH * NE * NS) return;
  const int h = g >> 14;
  atomicAdd(&counts[h * NV + edges[g]], 1);
}

__global__ void k_scan(const int* __restrict__ counts, int* __restrict__ offs,
                       float* __restrict__ invdeg, float* __restrict__ mvec) {
  const int h = blockIdx.x;
  const int tid = threadIdx.x;  // 1024 threads
  const int base = h * NV;
  const int CH = 10;
  int local[10];
  int run = 0;
  for (int i = 0; i < CH; ++i) {
    const int v = tid * CH + i;
    const int c = (v < NV) ? counts[base + v] : 0;
    local[i] = run; run += c;
  }
  __shared__ int sd[1024];
  sd[tid] = run;
  __syncthreads();
  int acc = run;
  for (int off = 1; off < 1024; off <<= 1) {
    const int t = (tid >= off) ? sd[tid - off] : 0;
    __syncthreads();
    acc += t; sd[tid] = acc;
    __syncthreads();
  }
  const int excl = acc - run;
  for (int i = 0; i < CH; ++i) {
    const int v = tid * CH + i;
    if (v < NV) {
      offs[base + v] = excl + local[i];
      const int c = counts[base + v];
      invdeg[base + v] = 1.0f / (float)((c > 0) ? c : 1);
      mvec[base + v] = (c > 0) ? 1.0f : 0.0f;
    }
  }
}

__global__ void k_fill(const int* __restrict__ edges, const int* __restrict__ offs,
                       int* __restrict__ cursor, int* __restrict__ slot_edge) {
  const int g = blockIdx.x * 256 + threadIdx.x;
  if (g >= NH * NE * NS) return;
  const int h = g >> 14;
  const int e = (g >> 5) & (NE - 1);
  const int v = edges[g];
  const int pos = atomicAdd(&cursor[h * NV + v], 1);
  slot_edge[h * NE * NS + offs[h * NV + v] + pos] = e;
}

// ---------------- per-branch graph compute (branch = blockIdx.y) ----------------
__global__ void k_trans2(const float* __restrict__ s0, const float* __restrict__ s1,
                         float* __restrict__ xT, int xtS) {
  __shared__ float tile[128][49];
  const float* seq = blockIdx.y ? s1 : s0;
  float* o = xT + (size_t)blockIdx.y * xtS;
  const int v0 = blockIdx.x * 128;
  const int tid = threadIdx.x;
  for (int i = tid; i < 128 * NSEQ; i += 256) {
    const int n = i / 128, vl = i % 128;
    const int v = v0 + vl;
    tile[vl][n] = (v < NV) ? seq[n * NV + v] : 0.0f;
  }
  __syncthreads();
  for (int i = tid; i < 128 * NSEQ; i += 256) {
    const int vl = i / NSEQ, n = i % NSEQ;
    const int v = v0 + vl;
    if (v < NV) o[v * NSEQ + n] = tile[vl][n];
  }
}

// float4 over n (NSEQ=48 -> 12 groups)
__global__ void k_eagg1(const int* __restrict__ edges, const float* __restrict__ xT,
                        int xtS, float* __restrict__ agg, int aggS) {
  const int g = blockIdx.x * 256 + threadIdx.x;
  if (g >= NH * NE * 12) return;
  const float* x = xT + (size_t)blockIdx.y * xtS;
  float* a = agg + (size_t)blockIdx.y * aggS;
  const int n0 = (g % 12) * 4;
  const int e = (g / 12) % NE;
  const int h = g / (12 * NE);
  const int* ep = edges + (h * NE + e) * NS;
  float4 acc = make_float4(0.f, 0.f, 0.f, 0.f);
  for (int s = 0; s < NS; ++s) {
    const float4 t = *(const float4*)&x[ep[s] * NSEQ + n0];
    acc.x += t.x; acc.y += t.y; acc.z += t.z; acc.w += t.w;
  }
  acc.x *= (1.0f / NS); acc.y *= (1.0f / NS); acc.z *= (1.0f / NS); acc.w *= (1.0f / NS);
  *(float4*)&a[(h * NE + e) * NSEQ + n0] = acc;
}

__global__ void k_eagg2(const int* __restrict__ edges, const float* __restrict__ ysum,
                        int yS, const float* __restrict__ invdeg,
                        float* __restrict__ agg, int aggS) {
  const int g = blockIdx.x * 256 + threadIdx.x;
  if (g >= NH * NE * 12) return;
  const float* y = ysum + (size_t)blockIdx.y * yS;
  float* a = agg + (size_t)blockIdx.y * aggS;
  const int n0 = (g % 12) * 4;
  const int e = (g / 12) % NE;
  const int h = g / (12 * NE);
  const int* ep = edges + (h * NE + e) * NS;
  float4 acc = make_float4(0.f, 0.f, 0.f, 0.f);
  for (int s = 0; s < NS; ++s) {
    const int v = ep[s];
    const float iv = invdeg[h * NV + v];
    const float4 t = *(const float4*)&y[(h * NV + v) * NSEQ + n0];
    acc.x += t.x * iv; acc.y += t.y * iv; acc.z += t.z * iv; acc.w += t.w * iv;
  }
  acc.x *= (1.0f / NS); acc.y *= (1.0f / NS); acc.z *= (1.0f / NS); acc.w *= (1.0f / NS);
  *(float4*)&a[(h * NE + e) * NSEQ + n0] = acc;
}

__global__ void k_vg(const int* __restrict__ counts, const int* __restrict__ offs,
                     const int* __restrict__ slot_edge, const float* __restrict__ agg,
                     int aggS, float* __restrict__ outv, int outS) {
  const int g = blockIdx.x * 256 + threadIdx.x;
  if (g >= NH * NV * 12) return;
  const float* a = agg + (size_t)blockIdx.y * aggS;
  float* o = outv + (size_t)blockIdx.y * outS;
  const int n0 = (g % 12) * 4;
  const int v = (g / 12) % NV;
  const int h = g / (12 * NV);
  const int beg = offs[h * NV + v];
  const int cnt = counts[h * NV + v];
  const int* se = slot_edge + h * NE * NS;
  float4 acc = make_float4(0.f, 0.f, 0.f, 0.f);
  for (int i = 0; i < cnt; ++i) {
    const int e = se[beg + i];
    const float4 t = *(const float4*)&a[(h * NE + e) * NSEQ + n0];
    acc.x += t.x; acc.y += t.y; acc.z += t.z; acc.w += t.w;
  }
  *(float4*)&o[(h * NV + v) * NSEQ + n0] = acc;  // unnormalized (divide folded downstream)
}

__global__ void k_attn(const float* __restrict__ zsum, int zS,
                       const float* __restrict__ invdeg, const float* __restrict__ mvec,
                       const float* __restrict__ ws, float* __restrict__ pq, int br0) {
  const int g = blockIdx.x * 256 + threadIdx.x;
  if (g >= NV * 12) return;
  const int bi = blockIdx.y;
  const float* z = zsum + (size_t)bi * zS;
  float* pbuf = pq + (size_t)(bi + br0) * 2 * NV * NSEQ;
  float* qbuf = pbuf + NV * NSEQ;
  const int n0 = (g % 12) * 4;
  const int v = g / 12;
  const float al = ws[S_SC + 0], be = ws[S_SC + 1], ga = ws[S_SC + 2],
              de = ws[S_SC + 3], ep = ws[S_SC + 4];
  union { float4 v4; float f[4]; } zh[3], pv, qv;
  float mh[3];
  #pragma unroll
  for (int h = 0; h < NH; ++h) {
    const float iv = invdeg[h * NV + v];
    float4 t = *(const float4*)&z[(h * NV + v) * NSEQ + n0];
    t.x *= iv; t.y *= iv; t.z *= iv; t.w *= iv;
    zh[h].v4 = t;
    mh[h] = mvec[h * NV + v];
  }
  const float mb = (mh[0] + mh[1] + mh[2]) * (1.f / 3.f);
  #pragma unroll
  for (int j = 0; j < 4; ++j) {
    const float z0 = zh[0].f[j], z1 = zh[1].f[j], z2 = zh[2].f[j];
    const float zb = (z0 + z1 + z2) * (1.f / 3.f);
    float sc[3];
    const float zt[3] = {z0, z1, z2};
    #pragma unroll
    for (int h = 0; h < NH; ++h) {
      const float s = al * zt[h] + be * mh[h] + ga * zb + de * mb + ep;
      sc[h] = (s > 0.f) ? s : 0.2f * s;
    }
    const float mx = fmaxf(sc[0], fmaxf(sc[1], sc[2]));
    const float e0 = __expf(sc[0] - mx), e1 = __expf(sc[1] - mx), e2 = __expf(sc[2] - mx);
    const float inv = 1.0f / (e0 + e1 + e2);
    pv.f[j] = (e0 * z0 + e1 * z1 + e2 * z2) * inv;
    qv.f[j] = (e0 * mh[0] + e1 * mh[1] + e2 * mh[2]) * inv;
  }
  *(float4*)&pbuf[v * NSEQ + n0] = pv.v4;
  *(float4*)&qbuf[v * NSEQ + n0] = qv.v4;
}

// ---------------- MFMA LSTM ----------------
// Block: 64 vertices (seqs), batch b = blockIdx.y, branch = blockIdx.z.
// gates = xg + h @ w_hh^T via mfma_f32_16x16x32_bf16; h carried as split bf16 hi+lo.
// w_hh staged once (no pad, 32768 B) into LDS; region then reused as h double-buffer.
// LDS total = 34816 (h dbuf) + 6144 (p/q) = 40960 B -> 4 blocks/CU.
#define RS  136  // h row stride (ushorts): 64 hi + 64 lo + 8 pad, 272 B (16B-aligned)
__launch_bounds__(256, 2)
__global__ void k_lstm2(const float* __restrict__ w_hh, const float* __restrict__ ws,
                        const float* __restrict__ pbase, const float* __restrict__ w_out,
                        float* __restrict__ part) {
  __shared__ __align__(16) unsigned short smem[2 * 64 * RS];  // 34816 B
  __shared__ float ps_sh[NTT][64], qs_sh[NTT][64];            // 6144 B
  const int tid = threadIdx.x;
  const int w = tid >> 6, lane = tid & 63, q = lane >> 4, l15 = lane & 15;
  const int b = blockIdx.y, br = blockIdx.z;
  const int v0 = blockIdx.x * 64;
  const int d = w * 16 + l15;  // this lane's gate-dim within [0,64)

  // coalesced stage: w_hh fp32 [256][64] -> smem bf16 [j][64] (no pad; one-time)
  for (int i = tid; i < 4096; i += 256) {
    const float4 w4 = ((const float4*)w_hh)[i];
    const int j = i >> 4, k = (i & 15) * 4;
    uint2 pk;
    pk.x = (unsigned int)f2bf(w4.x) | ((unsigned int)f2bf(w4.y) << 16);
    pk.y = (unsigned int)f2bf(w4.z) | ((unsigned int)f2bf(w4.w) << 16);
    *(uint2*)&smem[j * 64 + k] = pk;
  }
  // stage p,q for all 12 steps (float4 over t)
  const float* pp = pbase + (size_t)br * 2 * NV * NSEQ;
  const float* qq = pp + NV * NSEQ;
  for (int i = tid; i < 384; i += 256) {
    const int arr = (i >= 192) ? 1 : 0;
    const int ii = i - arr * 192;
    const int s = ii / 3, f4 = ii % 3;
    const int v = v0 + s;
    const float* src = arr ? qq : pp;
    float4 val = make_float4(0.f, 0.f, 0.f, 0.f);
    if (v < NV) val = *(const float4*)&src[v * NSEQ + b * NTT + f4 * 4];
    float (*dst)[64] = arr ? qs_sh : ps_sh;
    dst[f4 * 4 + 0][s] = val.x; dst[f4 * 4 + 1][s] = val.y;
    dst[f4 * 4 + 2][s] = val.z; dst[f4 * 4 + 3][s] = val.w;
  }
  __syncthreads();

  // B fragments from LDS: B[k][n=gate g*64+d], k = kh*32 + q*8 + j (one-time, conflicts ok)
  bf16x8 Bf[4][2];
  #pragma unroll
  for (int g = 0; g < 4; ++g)
    #pragma unroll
    for (int kh = 0; kh < 2; ++kh)
      Bf[g][kh] = ldsA(&smem[(g * 64 + d) * 64 + kh * 32 + q * 8]);

  float GUr[4], GCr[4], G0r[4];
  #pragma unroll
  for (int g = 0; g < 4; ++g) {
    GUr[g] = ws[S_GU + g * 64 + d];
    GCr[g] = ws[S_GC + g * 64 + d];
    G0r[g] = ws[S_G0 + g * 64 + d];
  }
  const float WO = w_out[br * 64 + d];
  __syncthreads();  // all waves done reading w-stage; reuse smem as h dbuf

  f32x4 acc[4][4];  // [mi seq-tile][g gate-type]
  f32x4 cst[4];
  float pr[4][4];   // last-step output partials (assigned at t==NTT-1)
  #pragma unroll
  for (int mi = 0; mi < 4; ++mi) cst[mi] = (f32x4){0.f, 0.f, 0.f, 0.f};

  #pragma unroll 1
  for (int t = 0; t < NTT; ++t) {
    // input contribution: xg = p*GU + q*GC + G0 (D layout: row s=mi*16+q*4+r, col d)
    #pragma unroll
    for (int mi = 0; mi < 4; ++mi)
      #pragma unroll
      for (int r = 0; r < 4; ++r) {
        const int s = mi * 16 + q * 4 + r;
        const float pv = ps_sh[t][s], qv = qs_sh[t][s];
        #pragma unroll
        for (int g = 0; g < 4; ++g)
          acc[mi][g][r] = fmaf(pv, GUr[g], fmaf(qv, GCr[g], G0r[g]));
      }
    if (t > 0) {
      const unsigned short* hr = smem + ((t - 1) & 1) * (64 * RS);
      #pragma unroll
      for (int kh = 0; kh < 2; ++kh)
        #pragma unroll
        for (int mi = 0; mi < 4; ++mi) {
          const int row = mi * 16 + l15;  // A layout: m = lane&15
          const int col = kh * 32 + q * 8;
          const bf16x8 Ahi = ldsA(&hr[row * RS + col]);
          const bf16x8 Alo = ldsA(&hr[row * RS + 64 + col]);
          #pragma unroll
          for (int g = 0; g < 4; ++g) {
            acc[mi][g] = __builtin_amdgcn_mfma_f32_16x16x32_bf16(Ahi, Bf[g][kh], acc[mi][g], 0, 0, 0);
            acc[mi][g] = __builtin_amdgcn_mfma_f32_16x16x32_bf16(Alo, Bf[g][kh], acc[mi][g], 0, 0, 0);
          }
        }
    }
    unsigned short* hw = smem + (t & 1) * (64 * RS);
    const bool last = (t == NTT - 1);
    #pragma unroll
    for (int mi = 0; mi < 4; ++mi)
      #pragma unroll
      for (int r = 0; r < 4; ++r) {
        const float ig = sigf(acc[mi][0][r]);
        const float fg = sigf(acc[mi][1][r]);
        const float gg = tanh_fast(acc[mi][2][r]);
        const float og = sigf(acc[mi][3][r]);
        const float cn = fmaf(fg, cst[mi][r], ig * gg);
        cst[mi][r] = cn;
        const float h = og * tanh_fast(cn);
        const int s = mi * 16 + q * 4 + r;
        if (!last) {
          const unsigned short hi = f2bf(h);
          const unsigned short lo = f2bf(h - bf2f(hi));
          hw[s * RS + d] = hi;
          hw[s * RS + 64 + d] = lo;
        } else {
          pr[mi][r] = h * WO;
        }
      }
    __syncthreads();
  }
  // cross-lane (16 dims of this wave) then cross-wave reduce via the dead h buffer
  float* fbuf = (float*)smem;
  #pragma unroll
  for (int mi = 0; mi < 4; ++mi)
    #pragma unroll
    for (int r = 0; r < 4; ++r) {
      float v = pr[mi][r];
      v += __shfl_xor(v, 1);
      v += __shfl_xor(v, 2);
      v += __shfl_xor(v, 4);
      v += __shfl_xor(v, 8);
      if (l15 == 0) fbuf[w * 64 + mi * 16 + q * 4 + r] = v;
    }
  __syncthreads();
  if (tid < 64) {
    const int v = v0 + tid;
    if (v < NV)
      part[(br * NB + b) * NV + v] =
          fbuf[tid] + fbuf[64 + tid] + fbuf[128 + tid] + fbuf[192 + tid];
  }
}

__global__ void k_comb(const float* __restrict__ part, const float* __restrict__ b_out,
                       float* __restrict__ out) {
  const int g = blockIdx.x * 256 + threadIdx.x;
  if (g >= NB * NV / 4) return;
  const float4 a = ((const float4*)part)[g];
  const float4 c = ((const float4*)part)[NB * NV / 4 + g];
  const float bo = b_out[0];
  float4 o;
  o.x = a.x + c.x + bo; o.y = a.y + c.y + bo;
  o.z = a.z + c.z + bo; o.w = a.w + c.w + bo;
  ((float4*)out)[g] = o;
}

extern "C" void kernel_launch(void* const* d_in, const int* in_sizes, int n_in,
                              void* d_out, int out_size, void* d_ws, size_t ws_size,
                              hipStream_t stream) {
  const float* tend   = (const float*)d_in[0];
  const float* peri   = (const float*)d_in[1];
  const int*   edges  = (const int*)d_in[2];
  const float* w1     = (const float*)d_in[3];
  const float* b1     = (const float*)d_in[4];
  const float* w2     = (const float*)d_in[5];
  const float* b2     = (const float*)d_in[6];
  const float* attn_w = (const float*)d_in[7];
  const float* attn_a = (const float*)d_in[8];
  const float* w_ih   = (const float*)d_in[9];
  const float* w_hh   = (const float*)d_in[10];
  const float* b_ih   = (const float*)d_in[11];
  const float* b_hh   = (const float*)d_in[12];
  const float* w_out  = (const float*)d_in[13];
  const float* b_out  = (const float*)d_in[14];
  float* out = (float*)d_out;
  float* ws  = (float*)d_ws;
  int*   iws = (int*)d_ws;
  int* cnt = iws + I_CNT;
  int* cur = iws + I_CUR;
  int* off = iws + I_OFF;
  int* sed = iws + I_SLOT;

  const size_t need2 = ((size_t)F_DYN + 2 * (XT_SZ + AGG_SZ + YZ_SZ)) * 4;
  const bool batched = ws_size >= need2;
  const int nb = batched ? 2 : 1;
  float* XT  = ws + F_DYN;
  float* AGG = XT + (size_t)nb * XT_SZ;
  float* YZ  = AGG + (size_t)nb * AGG_SZ;

  k_prep<<<1, 256, 0, stream>>>(w1, b1, w2, b2, attn_w, attn_a, w_ih, b_ih, b_hh, ws);
  k_zero<<<(2 * NH * NV + 255) / 256, 256, 0, stream>>>(cnt, 2 * NH * NV);
  k_count<<<(NH * NE * NS) / 256, 256, 0, stream>>>(edges, cnt);
  k_scan<<<NH, 1024, 0, stream>>>(cnt, off, ws + F_INV, ws + F_M);
  k_fill<<<(NH * NE * NS) / 256, 256, 0, stream>>>(edges, off, cur, sed);

  const int g_eagg = (NH * NE * 12 + 255) / 256;
  const int g_vg   = (NH * NV * 12 + 255) / 256;
  const int g_attn = (NV * 12 + 255) / 256;
  if (batched) {
    k_trans2<<<dim3((NV + 127) / 128, 2), 256, 0, stream>>>(tend, peri, XT, XT_SZ);
    k_eagg1<<<dim3(g_eagg, 2), 256, 0, stream>>>(edges, XT, XT_SZ, AGG, AGG_SZ);
    k_vg<<<dim3(g_vg, 2), 256, 0, stream>>>(cnt, off, sed, AGG, AGG_SZ, YZ, YZ_SZ);
    k_eagg2<<<dim3(g_eagg, 2), 256, 0, stream>>>(edges, YZ, YZ_SZ, ws + F_INV, AGG, AGG_SZ);
    k_vg<<<dim3(g_vg, 2), 256, 0, stream>>>(cnt, off, sed, AGG, AGG_SZ, YZ, YZ_SZ);
    k_attn<<<dim3(g_attn, 2), 256, 0, stream>>>(YZ, YZ_SZ, ws + F_INV, ws + F_M, ws, ws + F_PQ, 0);
  } else {
    for (int br = 0; br < 2; ++br) {
      const float* seq = br ? peri : tend;
      k_trans2<<<dim3((NV + 127) / 128, 1), 256, 0, stream>>>(seq, seq, XT, 0);
      k_eagg1<<<dim3(g_eagg, 1), 256, 0, stream>>>(edges, XT, 0, AGG, 0);
      k_vg<<<dim3(g_vg, 1), 256, 0, stream>>>(cnt, off, sed, AGG, 0, YZ, 0);
      k_eagg2<<<dim3(g_eagg, 1), 256, 0, stream>>>(edges, YZ, 0, ws + F_INV, AGG, 0);
      k_vg<<<dim3(g_vg, 1), 256, 0, stream>>>(cnt, off, sed, AGG, 0, YZ, 0);
      k_attn<<<dim3(g_attn, 1), 256, 0, stream>>>(YZ, 0, ws + F_INV, ws + F_M, ws, ws + F_PQ, br);
    }
  }
  dim3 lgrid((NV + 63) / 64, NB, 2);
  k_lstm2<<<lgrid, 256, 0, stream>>>(w_hh, ws, ws + F_PQ, w_out, ws + F_HT);
  k_comb<<<(NB * NV / 4 + 255) / 256, 256, 0, stream>>>(ws + F_HT, b_out, out);
}